// Round 6
// baseline (177.807 us; speedup 1.0000x reference)
//
#include <hip/hip_runtime.h>

// Depthwise cross-correlation: z (64,256,7,7) over x (64,256,31,31) VALID
// -> out (64,256,25,25), scaled 0.001. fp32 end-to-end.
//
// Round 13: R12 producer/consumer + z staged in LDS -> consumers issue
// ZERO VMEM loads.
//   R12 post-mortem: still in the 37-40us band. Leak found: consumers read
//   z from a GLOBAL pointer. If hipcc emits per-lane global_load (not
//   s_load), every FMA group gets s_waitcnt vmcnt(k); vmcnt retires
//   IN-ORDER, so each wait drains the previous slice's output stores ->
//   consumers re-couple to store latency + HBM backpressure every slice.
//   (R7, the best dur_us so far, read z from LDS -- consistent.)
//   Fix: producer stages z (147 dw/round, ONE gl_lds) into a z LDS buffer;
//   consumers read w[j] via LDS broadcast (uniform addr, conflict-free,
//   lgkm-only). Consumer VMEM = fire-and-forget stores ONLY: nothing in the
//   consumer loop can wait on vmcnt. All load latency lives in the producer.
//   Structure otherwise = R12: 3 consumer + 1 producer wave, 1536 blocks
//   (6/CU resident, 26KB LDS), double-buffered halves, raw s_barrier
//   rounds, out-stage into consumed x, coalesced copy-out.

#define KH 7
#define KW 7
#define XW 31
#define OH 25
#define OW 25
#define NSLICE (64 * 256)
#define THREADS 256
#define NBLK 1536                      // 6 blocks/CU x 256 CU, all resident
#define RND 4                          // 1536*3*4 = 18432 >= 16384 slices
#define HALF_DW 3072                   // 3 slices (2883 dw) + align slack
#define ZHALF_DW 256                   // 147 dw + slack, one gl_lds cover
#define SLICE_X (XW * XW)              // 961
#define SLICE_O (OH * OW)              // 625
#define X_TOTAL_DW (NSLICE * SLICE_X)  // 15,745,024
#define Z_TOTAL_DW (NSLICE * KH * KW)  // 802,816

__device__ __forceinline__ void gl_lds16(const float* g, float* l) {
    __builtin_amdgcn_global_load_lds(
        (const __attribute__((address_space(1))) void*)g,
        (__attribute__((address_space(3))) void*)l, 16, 0, 0);
}

// Producer: stage 3 contiguous x slices (2883 dw + slack) = 12 x (64 x 16 B).
__device__ __forceinline__ void stage3(const float* __restrict__ x,
                                       float* __restrict__ half,
                                       int sbase, int lane) {
    const int g0 = (sbase * SLICE_X) & ~3;     // 16B-aligned; slack in [0,3]
    #pragma unroll
    for (int k = 0; k < 12; ++k) {
        const int dw = k * 256 + lane * 4;
        gl_lds16(x + min(g0 + dw, X_TOTAL_DW - 4), half + dw);  // clamp: tail/idle
    }
}

// Producer: stage 3 slices of z (147 dw + slack) in ONE gl_lds instr.
__device__ __forceinline__ void stagez(const float* __restrict__ z,
                                       float* __restrict__ zhalf,
                                       int sbase, int lane) {
    const int g0 = (sbase * KH * KW) & ~3;     // slack in [0,3]
    gl_lds16(z + min(g0 + lane * 4, Z_TOTAL_DW - 4), zhalf + lane * 4);
}

__global__ __launch_bounds__(THREADS, 6)
void xcorr_dw_kernel(const float* __restrict__ z,
                     const float* __restrict__ x,
                     float* __restrict__ out) {
    __shared__ float xs[2][HALF_DW];           // 24 KB x double buffer
    __shared__ float zs[2][ZHALF_DW];          // 2 KB  z double buffer
    const int lane = threadIdx.x & 63;
    const int wv   = __builtin_amdgcn_readfirstlane(threadIdx.x >> 6);
    const int b    = blockIdx.x;               // block owns slices [12b, 12b+12)

    if (wv == 3) {
        // ---------------- producer wave ----------------
        stage3(x, xs[0], 12 * b, lane);
        stagez(z, zs[0], 12 * b, lane);
        asm volatile("s_waitcnt vmcnt(0)" ::: "memory");
        __builtin_amdgcn_sched_barrier(0);
        #pragma unroll 1
        for (int r = 0; r < RND; ++r) {
            __builtin_amdgcn_s_barrier();      // B_r: round r data published
            if (r + 1 < RND) {
                // Fill the half consumers vacated (round r-1's buffer).
                stage3(x, xs[(r + 1) & 1], 12 * b + 3 * (r + 1), lane);
                stagez(z, zs[(r + 1) & 1], 12 * b + 3 * (r + 1), lane);
                asm volatile("s_waitcnt vmcnt(0)" ::: "memory");
                __builtin_amdgcn_sched_barrier(0);
            }
        }
    } else {
        // ------------- consumer waves (wv = 0,1,2): NO VMEM loads -------------
        const int h   = (lane >= OH) ? 1 : 0;
        const int oy  = h ? lane - OH : lane;
        const int c0  = h ? 13 : 0;            // h=0: cols 0..12, h=1: 13..24
        const bool act = (lane < 2 * OH);
        #pragma unroll 1
        for (int r = 0; r < RND; ++r) {
            __builtin_amdgcn_s_barrier();      // wait for producer's round r
            const int sbase = 12 * b + 3 * r;
            const int s     = sbase + wv;
            if (s < NSLICE) {
                const int pre  = (sbase * SLICE_X) & 3;
                const int zpre = (sbase * KH * KW) & 3;
                float* __restrict__ buf = xs[r & 1] + pre + wv * SLICE_X;
                const float* __restrict__ zrow = zs[r & 1] + zpre + wv * (KH * KW);
                if (act) {
                    float acc[13] = {};
                    #pragma unroll
                    for (int i = 0; i < KH; ++i) {
                        // w[0..6] from LDS, uniform addr -> broadcast, lgkm-only
                        float w[KW];
                        #pragma unroll
                        for (int j = 0; j < KW; ++j) w[j] = zrow[i * KW + j];
                        const float* __restrict__ p = buf + (oy + i) * XW + c0;
                        float f[19];           // h=1's f[18] = next slice's dw0:
                        #pragma unroll         // in-LDS-bounds, feeds dead acc[12]
                        for (int c = 0; c < 19; ++c) f[c] = p[c];
                        #pragma unroll
                        for (int j = 0; j < KW; ++j) {
                            #pragma unroll
                            for (int c = 0; c < 13; ++c)
                                acc[c] = fmaf(f[c + j], w[j], acc[c]);
                        }
                    }
                    // Out-stage into own consumed x region [0,625) of buf.
                    const int fb = oy * OW + c0;
                    #pragma unroll
                    for (int c = 0; c < 12; ++c) buf[fb + c] = acc[c] * 0.001f;
                    if (c0 == 0) buf[fb + 12] = acc[12] * 0.001f;
                }
                // Coalesced copy-out: 625 dw = 9 x 64 + 49 tail (fire-and-forget).
                float* __restrict__ og = out + (size_t)s * SLICE_O;
                #pragma unroll
                for (int k = 0; k < 9; ++k) og[k * 64 + lane] = buf[k * 64 + lane];
                if (lane < SLICE_O - 576) og[576 + lane] = buf[576 + lane];
            }
        }
    }
}

extern "C" void kernel_launch(void* const* d_in, const int* in_sizes, int n_in,
                              void* d_out, int out_size, void* d_ws, size_t ws_size,
                              hipStream_t stream) {
    const float* z = (const float*)d_in[0];   // (64,256,7,7)
    const float* x = (const float*)d_in[1];   // (64,256,31,31)
    float* out = (float*)d_out;               // (64,256,25,25)
    xcorr_dw_kernel<<<dim3(NBLK), dim3(THREADS), 0, stream>>>(z, x, out);
}

// Round 7
// 114.178 us; speedup vs baseline: 1.5573x; 1.5573x over previous
//
#include <hip/hip_runtime.h>

// Depthwise cross-correlation: z (64,256,7,7) over x (64,256,31,31) VALID
// -> out (64,256,25,25), scaled 0.001. fp32 end-to-end.
//
// Round 14: minimum-lifetime autonomous waves. One slice per WAVE, zero
// barriers, zero inter-wave coupling, 32 waves/CU.
//   R13 post-mortem: VGPR_Count=40 + WRITE 191MB = f[19]+w[7] spilled to
//   scratch (3rd spill incident) -- weights must live in SGPRs, not VGPRs.
//   R12 re-audit: its consumer z index was blockIdx/readfirstlane-uniform
//   -> already s_load; clean producer/consumer STILL ~40us => specialization
//   doesn't beat the wall. New model: per-block lifetime = [stage-wait]
//   [compute ~10us-share]; only ~2 residency generations, so gen-1's load
//   wait and gen-2's compute are fully exposed: T ~ fill + 2*C = 37us for
//   every coarse-lifetime variant (R7 5-slice, R8 2/wave, R12 12/block).
//   Fix: shrink lifetime to ONE slice per wave (~1.8us) -> ~8 effective
//   generations, fill/drain ~2us, per-wave load-waits naturally stagger
//   against other waves' compute. 8192 blocks x 128 thr; 8KB LDS/block ->
//   up to 16 blocks/CU = 32 waves/CU (R7 had 14, R8 20). launch_bounds
//   (128,6) caps VGPR at 80 (need ~55: acc13+f19+addr; z via s_load SGPRs).
//   No __syncthreads anywhere: all LDS hazards are same-wave program-order
//   (compute ds_reads precede out-stage ds_writes precede copy ds_reads).

#define KH 7
#define KW 7
#define XW 31
#define OH 25
#define OW 25
#define NSLICE (64 * 256)
#define THREADS 128
#define NBLK (NSLICE / 2)              // 8192 blocks, 1 slice per wave, exact
#define BUF_DW 1024                    // 4 KB/wave: pre + 961 <= 964
#define SLICE_X (XW * XW)              // 961
#define SLICE_O (OH * OW)              // 625
#define X_TOTAL_DW (NSLICE * SLICE_X)  // 15,745,024

__device__ __forceinline__ void gl_lds16(const float* g, float* l) {
    __builtin_amdgcn_global_load_lds(
        (const __attribute__((address_space(1))) void*)g,
        (__attribute__((address_space(3))) void*)l, 16, 0, 0);
}

__global__ __launch_bounds__(THREADS, 6)
void xcorr_dw_kernel(const float* __restrict__ z,
                     const float* __restrict__ x,
                     float* __restrict__ out) {
    __shared__ float xs[2][BUF_DW];            // 8 KB: one 4 KB buffer per wave
    const int lane = threadIdx.x & 63;
    const int wv   = __builtin_amdgcn_readfirstlane(threadIdx.x >> 6);
    float* __restrict__ buf = xs[wv];

    const int s = blockIdx.x * 2 + wv;         // slice id, wave-uniform

    // ---- stage this wave's slice: 4 x (64 lanes x 16 B) = 1024 dwords.
    const int g0r = s * SLICE_X;
    const int pre = g0r & 3;                   // 16B-align slack in [0,3]
    const int g0  = g0r - pre;
    #pragma unroll
    for (int k = 0; k < 4; ++k) {
        const int dw = k * 256 + lane * 4;
        gl_lds16(x + min(g0 + dw, X_TOTAL_DW - 4), buf + dw);   // clamp: last slice
    }

    // z weights: s is uniform -> s_load into SGPRs (zero VGPR cost).
    const float* __restrict__ zw = z + (size_t)s * (KH * KW);

    // lane -> (col-half h, row oy); 50/64 lanes active in compute.
    const int h   = (lane >= OH) ? 1 : 0;
    const int oy  = h ? lane - OH : lane;
    const int c0  = h ? 13 : 0;                // h=0: cols 0..12, h=1: 13..24
    const bool act = (lane < 2 * OH);

    // Wait for THIS wave's 4 loads only (nothing else outstanding).
    asm volatile("s_waitcnt vmcnt(0)" ::: "memory");
    __builtin_amdgcn_sched_barrier(0);

    if (act) {
        float acc[13] = {};
        const float* __restrict__ xrow = buf + pre;
        #pragma unroll
        for (int i = 0; i < KH; ++i) {
            const float* __restrict__ p = xrow + (oy + i) * XW + c0;
            float f[19];                       // h=1's f[18] = next row dw0:
            #pragma unroll                     // in-LDS-bounds, feeds dead lane-col
            for (int c = 0; c < 19; ++c) f[c] = p[c];
            #pragma unroll
            for (int j = 0; j < KW; ++j) {
                const float w = zw[i * KW + j];   // SGPR operand of v_fmac
                #pragma unroll
                for (int c = 0; c < 13; ++c)
                    acc[c] = fmaf(f[c + j], w, acc[c]);
            }
        }
        // Out-stage into consumed x region [0,625) (same-wave DS order).
        const int fb = oy * OW + c0;
        #pragma unroll
        for (int c = 0; c < 12; ++c) buf[fb + c] = acc[c] * 0.001f;
        if (!h) buf[fb + 12] = acc[12] * 0.001f;   // h=0 owns col 12
    }

    // Coalesced copy-out: 625 dw = 9 x 64 + 49 tail (fire-and-forget stores).
    float* __restrict__ og = out + (size_t)s * SLICE_O;
    #pragma unroll
    for (int k = 0; k < 9; ++k) og[k * 64 + lane] = buf[k * 64 + lane];
    if (lane < SLICE_O - 576) og[576 + lane] = buf[576 + lane];
}

extern "C" void kernel_launch(void* const* d_in, const int* in_sizes, int n_in,
                              void* d_out, int out_size, void* d_ws, size_t ws_size,
                              hipStream_t stream) {
    const float* z = (const float*)d_in[0];   // (64,256,7,7)
    const float* x = (const float*)d_in[1];   // (64,256,31,31)
    float* out = (float*)d_out;               // (64,256,25,25)
    xcorr_dw_kernel<<<dim3(NBLK), dim3(THREADS), 0, stream>>>(z, x, out);
}